// Round 9
// baseline (167.303 us; speedup 1.0000x reference)
//
#include <hip/hip_runtime.h>
#include <stdint.h>

// VQ: inputs (16,64,64,64) f32 BCHW, codebook (1024,64) f32.
// out[0:65536] = argmin indices as float; out[65536:] = gathered rows, BCHW.
//
// r9: NO LDS staging of the codebook (it is 256 KB, L2-resident; r7/r8 showed
// LDS restage + barriers + per-wave ds_read re-reads are pure overhead).
// Prep kernel writes split bf16 hi/lo codebook into d_ws in FRAGMENT ORDER:
// ktile kt (16 codes), lane l's 16B at kt*4096 + {ks,hi/lo}*1024 + l*16.
// Main loop: 4 coalesced global dwordx4 per ktile from L2, 12 MFMA
// (2 n-frags x 2 ks x 3 hi/lo passes), zero barriers. Wave owns 32 positions.
// Numerics r4-r8 validated: 3-pass bf16-split MFMA filter, packed (s|k) keys
// (first-occurrence tiebreak), BIAS=0.25 keeps s>0, DELTA=1e-4 gap -> exact
// rescreen with bit-exact numpy pairwise znorm and t/u/d fp32 op order.
#define NUM_K 1024
#define CDIM  64
#define NPOS  65536
#define NPB   128      // 4 waves * 32 positions
#define DELTA 1e-4f
#define BIAS  0.25f

typedef __attribute__((ext_vector_type(8))) short short8;
typedef __attribute__((ext_vector_type(4))) float f32x4;

union U4S8 { uint4 u; short8 s; };

// ---- d_ws layout (bytes) ----
#define WS_CNORM 0         // 1024 f32 exact
#define WS_CNB   4096      // 1024 f32 (cnorm + BIAS)
#define WS_CBF   8192      // 64 ktiles * 4096 B:
                           //   + 0    : ks0 hi  (lane l -> 16B at l*16)
                           //   + 1024 : ks0 lo
                           //   + 2048 : ks1 hi
                           //   + 3072 : ks1 lo

__device__ __forceinline__ void cvt_pair(float f0, float f1,
                                         uint32_t& hp, uint32_t& lp) {
    uint32_t h;
    asm("v_cvt_pk_bf16_f32 %0, %1, %2" : "=v"(h) : "v"(f0), "v"(f1));
    float h0 = __uint_as_float(h << 16);
    float h1 = __uint_as_float(h & 0xFFFF0000u);
    float r0 = f0 - h0, r1 = f1 - h1;
    uint32_t l;
    asm("v_cvt_pk_bf16_f32 %0, %1, %2" : "=v"(l) : "v"(r0), "v"(r1));
    hp = h; lp = l;
}

__device__ __forceinline__ unsigned long long shflxor64(unsigned long long v, int off) {
    unsigned lo = (unsigned)v, hi = (unsigned)(v >> 32);
    lo = (unsigned)__shfl_xor((int)lo, off);
    hi = (unsigned)__shfl_xor((int)hi, off);
    return ((unsigned long long)hi << 32) | lo;
}

// ---- kernel 1: cnorm (exact pairwise) + fragment-ordered bf16 hi/lo ----
__global__ __launch_bounds__(256) void vq_prep_kernel(
    const float* __restrict__ cb, unsigned char* __restrict__ ws) {
#pragma clang fp contract(off)
    const int k = blockIdx.x * 256 + threadIdx.x;   // grid = 4 blocks
    const float4* row4 = (const float4*)(cb + k * CDIM);
    float v[CDIM];
#pragma unroll
    for (int i = 0; i < 16; ++i) {
        float4 t = row4[i];
        v[i * 4 + 0] = t.x; v[i * 4 + 1] = t.y;
        v[i * 4 + 2] = t.z; v[i * 4 + 3] = t.w;
    }
    float r[8];
#pragma unroll
    for (int j = 0; j < 8; ++j) r[j] = v[j] * v[j];
#pragma unroll
    for (int i = 1; i < 8; ++i) {
#pragma unroll
        for (int j = 0; j < 8; ++j) {
            float s = v[i * 8 + j] * v[i * 8 + j];
            r[j] = r[j] + s;
        }
    }
    const float cn =
        ((r[0] + r[1]) + (r[2] + r[3])) + ((r[4] + r[5]) + (r[6] + r[7]));
    ((float*)(ws + WS_CNORM))[k] = cn;
    ((float*)(ws + WS_CNB))[k]   = cn + BIAS;

    // fragment-order split: code k = kt*16 + rr; slot s (dims s*8..s*8+7):
    //   ks = s>>2, lane = (s&3)*16 + rr
    const int kt = k >> 4, rr = k & 15;
    unsigned char* base = ws + WS_CBF + kt * 4096;
#pragma unroll
    for (int s = 0; s < 8; ++s) {
        U4S8 H, L;
        uint32_t hp, lp;
        cvt_pair(v[s * 8 + 0], v[s * 8 + 1], hp, lp); H.u.x = hp; L.u.x = lp;
        cvt_pair(v[s * 8 + 2], v[s * 8 + 3], hp, lp); H.u.y = hp; L.u.y = lp;
        cvt_pair(v[s * 8 + 4], v[s * 8 + 5], hp, lp); H.u.z = hp; L.u.z = lp;
        cvt_pair(v[s * 8 + 6], v[s * 8 + 7], hp, lp); H.u.w = hp; L.u.w = lp;
        const int ks   = s >> 2;
        const int lane = (s & 3) * 16 + rr;
        unsigned char* hi_dst = base + ks * 2048 + lane * 16;
        *(uint4*)(hi_dst)        = H.u;
        *(uint4*)(hi_dst + 1024) = L.u;
    }
}

// ---- LDS layout (bytes) ----
#define LDS_CNB  0         // 4096 (main loop only; overlaid by tile later)
#define LDS_TILE 0         // 128*65*4 = 33280 (epilogue)
#define LDS_SFIN 33280     // 128 int
#define LDS_AMBC 33792
#define LDS_AMBL 33796     // 128 int
#define LDS_ZSC  34320     // 4 waves * 64 f32 (16B aligned)
#define SMEM_SZ  35344

// ---- kernel 2: main ----
__global__ __launch_bounds__(256, 2) void vq_main_kernel(
    const float* __restrict__ in, const float* __restrict__ cb,
    const unsigned char* __restrict__ ws, float* __restrict__ out) {
#pragma clang fp contract(off)
    const int tid  = threadIdx.x;
    const int lane = tid & 63;
    const int wv   = tid >> 6;          // 0..3
    const int l15  = lane & 15;
    const int lg   = lane >> 4;         // 0..3
    const int n0g  = blockIdx.x * NPB;
    const int b    = n0g >> 12;
    const int hw0  = n0g & 4095;

    __shared__ __align__(16) unsigned char smem[SMEM_SZ];
    float* cnb_l   = (float*)(smem + LDS_CNB);
    int*   sfin    = (int*)(smem + LDS_SFIN);
    int*   ambcnt  = (int*)(smem + LDS_AMBC);
    int*   amblist = (int*)(smem + LDS_AMBL);
    float* zsc     = (float*)(smem + LDS_ZSC);
    const unsigned char* cbf = ws + WS_CBF;
    const float* cnorm = (const float*)(ws + WS_CNORM);

    if (tid == 0) *ambcnt = 0;

    // ---- stage cnb into LDS (4 KB) ----
#pragma unroll
    for (int i = 0; i < 4; ++i)
        cnb_l[i * 256 + tid] = ((const float*)(ws + WS_CNB))[i * 256 + tid];

    // ---- z frags from global: wave owns 32 positions (2 n-frags) ----
    // lane l, n-frag na: position wv*32 + na*16 + l15, dims slot ks*4+lg
    short8 zfh[2][2], zfl[2][2];   // [na][ks]
#pragma unroll
    for (int na = 0; na < 2; ++na) {
        const int pos = wv * 32 + na * 16 + l15;
#pragma unroll
        for (int ks = 0; ks < 2; ++ks) {
            const int sl = ks * 4 + lg;
            const float* zp = in + (((size_t)(b * CDIM + sl * 8)) << 12) + hw0 + pos;
            float f[8];
#pragma unroll
            for (int j = 0; j < 8; ++j) f[j] = zp[(size_t)j << 12];
            U4S8 H, L;
            uint32_t hp, lp;
            cvt_pair(f[0], f[1], hp, lp); H.u.x = hp; L.u.x = lp;
            cvt_pair(f[2], f[3], hp, lp); H.u.y = hp; L.u.y = lp;
            cvt_pair(f[4], f[5], hp, lp); H.u.z = hp; L.u.z = lp;
            cvt_pair(f[6], f[7], hp, lp); H.u.w = hp; L.u.w = lp;
            zfh[na][ks] = H.s; zfl[na][ks] = L.s;
        }
    }
    __syncthreads();   // cnb ready

    const float finf = __uint_as_float(0x7F800000u);
    float m1[2] = {finf, finf}, m2[2] = {finf, finf};

    // ---- main loop: 64 ktiles, register double-buffered, ZERO barriers ----
    const unsigned char* fb0 = cbf + (size_t)lane * 16;
    U4S8 ch0, cl0, ch1, cl1;
    ch0.u = *(const uint4*)(fb0);
    cl0.u = *(const uint4*)(fb0 + 1024);
    ch1.u = *(const uint4*)(fb0 + 2048);
    cl1.u = *(const uint4*)(fb0 + 3072);

    for (int kt = 0; kt < 64; ++kt) {
        U4S8 nh0, nl0, nh1, nl1;
        if (kt < 63) {
            const unsigned char* fb = cbf + (kt + 1) * 4096 + (size_t)lane * 16;
            nh0.u = *(const uint4*)(fb);
            nl0.u = *(const uint4*)(fb + 1024);
            nh1.u = *(const uint4*)(fb + 2048);
            nl1.u = *(const uint4*)(fb + 3072);
        }

        const int kb = kt * 16 + lg * 4;
        const f32x4 cn = *(const f32x4*)(cnb_l + kb);

        f32x4 a0 = {0.f, 0.f, 0.f, 0.f}, a1 = {0.f, 0.f, 0.f, 0.f};
        a0 = __builtin_amdgcn_mfma_f32_16x16x32_bf16(cl0.s, zfh[0][0], a0, 0, 0, 0);
        a1 = __builtin_amdgcn_mfma_f32_16x16x32_bf16(cl0.s, zfh[1][0], a1, 0, 0, 0);
        a0 = __builtin_amdgcn_mfma_f32_16x16x32_bf16(ch0.s, zfl[0][0], a0, 0, 0, 0);
        a1 = __builtin_amdgcn_mfma_f32_16x16x32_bf16(ch0.s, zfl[1][0], a1, 0, 0, 0);
        a0 = __builtin_amdgcn_mfma_f32_16x16x32_bf16(ch0.s, zfh[0][0], a0, 0, 0, 0);
        a1 = __builtin_amdgcn_mfma_f32_16x16x32_bf16(ch0.s, zfh[1][0], a1, 0, 0, 0);
        a0 = __builtin_amdgcn_mfma_f32_16x16x32_bf16(cl1.s, zfh[0][1], a0, 0, 0, 0);
        a1 = __builtin_amdgcn_mfma_f32_16x16x32_bf16(cl1.s, zfh[1][1], a1, 0, 0, 0);
        a0 = __builtin_amdgcn_mfma_f32_16x16x32_bf16(ch1.s, zfl[0][1], a0, 0, 0, 0);
        a1 = __builtin_amdgcn_mfma_f32_16x16x32_bf16(ch1.s, zfl[1][1], a1, 0, 0, 0);
        a0 = __builtin_amdgcn_mfma_f32_16x16x32_bf16(ch1.s, zfh[0][1], a0, 0, 0, 0);
        a1 = __builtin_amdgcn_mfma_f32_16x16x32_bf16(ch1.s, zfh[1][1], a1, 0, 0, 0);

#pragma unroll
        for (int r = 0; r < 4; ++r) {
            float s0 = fmaf(-2.0f, a0[r], cn[r]);
            float k0 = __uint_as_float(
                (__float_as_uint(s0) & 0xFFFFFC00u) | (uint32_t)(kb + r));
            m2[0] = fminf(m2[0], fmaxf(k0, m1[0]));
            m1[0] = fminf(m1[0], k0);
            float s1 = fmaf(-2.0f, a1[r], cn[r]);
            float k1 = __uint_as_float(
                (__float_as_uint(s1) & 0xFFFFFC00u) | (uint32_t)(kb + r));
            m2[1] = fminf(m2[1], fmaxf(k1, m1[1]));
            m1[1] = fminf(m1[1], k1);
        }

        ch0 = nh0; cl0 = nl0; ch1 = nh1; cl1 = nl1;
    }

    // ---- merge the 4 k-lane-groups (lanes l15, +16, +32, +48) ----
#pragma unroll
    for (int na = 0; na < 2; ++na) {
#pragma unroll
        for (int off = 16; off <= 32; off <<= 1) {
            float o1 = __shfl_xor(m1[na], off);
            float o2 = __shfl_xor(m2[na], off);
            m2[na] = fminf(fminf(m2[na], o2), fmaxf(m1[na], o1));
            m1[na] = fminf(m1[na], o1);
        }
    }

    // ---- finalize: lg==0 lanes own position wv*32 + na*16 + l15 ----
    if (lg == 0) {
#pragma unroll
        for (int na = 0; na < 2; ++na) {
            const int n = wv * 32 + na * 16 + l15;
            const uint32_t u1 = __float_as_uint(m1[na]);
            const int idx = (int)(u1 & 1023u);
            sfin[n] = idx;
            out[n0g + n] = (float)idx;
            const float v1 = __uint_as_float(u1 & 0xFFFFFC00u);
            const float v2 = __uint_as_float(__float_as_uint(m2[na]) & 0xFFFFFC00u);
            if (v2 - v1 < DELTA) {
                int p = atomicAdd(ambcnt, 1);
                amblist[p] = n;
            }
        }
    }
    __syncthreads();

    // ---- exact rescreen, wave-parallel (r7-validated numerics) ----
    const int namb = *ambcnt;
    for (int i = wv; i < namb; i += 4) {
        const int n = amblist[i];
        float zc = in[(((size_t)(b * CDIM + lane)) << 12) + hw0 + n];
        float sq = zc * zc;
        float accp = sq;
#pragma unroll
        for (int i2 = 1; i2 < 8; ++i2)
            accp = accp + __shfl(sq, i2 * 8 + (lane & 7));
        float t1 = accp + __shfl_xor(accp, 1);
        float t2 = t1 + __shfl_xor(t1, 2);
        float t3 = t2 + __shfl_xor(t2, 4);
        const float zn = __shfl(t3, 0);
        zsc[wv * 64 + lane] = zc;
        const float* zrow = &zsc[wv * 64];
        unsigned long long bestk = ~0ull;
        for (int j = 0; j < 16; ++j) {
            const int k = j * 64 + lane;
            const float4* e = (const float4*)(cb + (size_t)k * CDIM);
            float a0 = 0.f, a1 = 0.f, a2 = 0.f, a3 = 0.f;
#pragma unroll
            for (int i2 = 0; i2 < 4; ++i2) {
                float4 zz = *(const float4*)(zrow + i2 * 16);
                float4 z1 = *(const float4*)(zrow + i2 * 16 + 4);
                float4 z2 = *(const float4*)(zrow + i2 * 16 + 8);
                float4 z3 = *(const float4*)(zrow + i2 * 16 + 12);
                float4 v0 = e[i2 * 4 + 0];
                float4 v1 = e[i2 * 4 + 1];
                float4 v2 = e[i2 * 4 + 2];
                float4 v3 = e[i2 * 4 + 3];
                a0 = fmaf(zz.x, v0.x, a0); a0 = fmaf(zz.y, v0.y, a0);
                a0 = fmaf(zz.z, v0.z, a0); a0 = fmaf(zz.w, v0.w, a0);
                a1 = fmaf(z1.x, v1.x, a1); a1 = fmaf(z1.y, v1.y, a1);
                a1 = fmaf(z1.z, v1.z, a1); a1 = fmaf(z1.w, v1.w, a1);
                a2 = fmaf(z2.x, v2.x, a2); a2 = fmaf(z2.y, v2.y, a2);
                a2 = fmaf(z2.z, v2.z, a2); a2 = fmaf(z2.w, v2.w, a2);
                a3 = fmaf(z3.x, v3.x, a3); a3 = fmaf(z3.y, v3.y, a3);
                a3 = fmaf(z3.z, v3.z, a3); a3 = fmaf(z3.w, v3.w, a3);
            }
            float dot = (a0 + a1) + (a2 + a3);
            float t = zn + cnorm[k];   // fl(znorm + cnorm)
            float u = 2.0f * dot;      // fl(2*dot)
            float d = t - u;           // fl(t - u)
            unsigned long long key =
                ((unsigned long long)__float_as_uint(d) << 10) | (unsigned)k;
            bestk = key < bestk ? key : bestk;
        }
#pragma unroll
        for (int off = 32; off >= 1; off >>= 1) {
            unsigned long long o = shflxor64(bestk, off);
            bestk = o < bestk ? o : bestk;
        }
        if (lane == 0) {
            const int idx = (int)(bestk & 1023u);
            sfin[n] = idx;
            out[n0g + n] = (float)idx;
        }
    }
    __syncthreads();

    // ---- zqs epilogue: gather -> LDS tile [128][65] -> coalesced BCHW ----
    float (*tile)[65] = (float (*)[65])(smem + LDS_TILE);
    {
        const int p = tid >> 1, half = tid & 1;     // p: 0..127
        const int idx = sfin[p];
        const float4* row = (const float4*)(cb + (size_t)idx * CDIM) + half * 8;
#pragma unroll
        for (int i = 0; i < 8; ++i) {
            float4 v = row[i];
            const int cch = half * 32 + i * 4;
            tile[p][cch + 0] = v.x; tile[p][cch + 1] = v.y;
            tile[p][cch + 2] = v.z; tile[p][cch + 3] = v.w;
        }
    }
    __syncthreads();
    {
        float* zq = out + NPOS + (((size_t)b * CDIM) << 12) + hw0;
#pragma unroll
        for (int i = 0; i < 16; ++i) {
            const int cch = i * 4 + wv;
#pragma unroll
            for (int h = 0; h < 2; ++h)
                zq[((size_t)cch << 12) + h * 64 + lane] = tile[h * 64 + lane][cch];
        }
    }
}

extern "C" void kernel_launch(void* const* d_in, const int* in_sizes, int n_in,
                              void* d_out, int out_size, void* d_ws, size_t ws_size,
                              hipStream_t stream) {
    const float* in = (const float*)d_in[0];   // 16*64*64*64
    const float* cb = (const float*)d_in[1];   // 1024*64
    float* out = (float*)d_out;                // 65536 + 4194304
    unsigned char* ws = (unsigned char*)d_ws;  // ~264 KB used

    vq_prep_kernel<<<NUM_K / 256, 256, 0, stream>>>(cb, ws);
    vq_main_kernel<<<NPOS / NPB, 256, 0, stream>>>(in, cb, ws, out);
}

// Round 10
// 153.339 us; speedup vs baseline: 1.0911x; 1.0911x over previous
//
#include <hip/hip_runtime.h>
#include <stdint.h>

// VQ: inputs (16,64,64,64) f32 BCHW, codebook (1024,64) f32.
// out[0:65536] = argmin indices as float; out[65536:] = gathered rows, BCHW.
//
// r10: CONCURRENCY round. r4-r9 all had identical busy time (VALU ~23us,
// MFMA ~10us) and 13-26% occupancy (grid 512 = 2 blocks/CU) -> duration was
// pure exposed latency at ~1 wave/SIMD. Fix: k-split. Block = 32 positions,
// 4 waves; wave wv scans k-quarter wv (256 codes, 16 ktiles) for all 32
// positions. Grid 2048 blocks -> ~5-6 resident blocks/CU (~20-24 waves/CU).
// Cross-wave merge via LDS packed keys (k embedded -> first-occurrence
// tiebreak survives any merge order). Codebook read straight from L2 in
// fragment order (r9 path). Numerics r4-r9 validated and unchanged.
#define NUM_K 1024
#define CDIM  64
#define NPOS  65536
#define NPB   32       // positions per block
#define DELTA 1e-4f
#define BIAS  0.25f

typedef __attribute__((ext_vector_type(8))) short short8;
typedef __attribute__((ext_vector_type(4))) float f32x4;

union U4S8 { uint4 u; short8 s; };

// ---- d_ws layout (bytes) ----
#define WS_CNORM 0         // 1024 f32 exact
#define WS_CNB   4096      // 1024 f32 (cnorm + BIAS)
#define WS_CBF   8192      // 64 ktiles * 4096 B (fragment order):
                           //   +0:ks0 hi  +1024:ks0 lo  +2048:ks1 hi  +3072:ks1 lo

__device__ __forceinline__ void cvt_pair(float f0, float f1,
                                         uint32_t& hp, uint32_t& lp) {
    uint32_t h;
    asm("v_cvt_pk_bf16_f32 %0, %1, %2" : "=v"(h) : "v"(f0), "v"(f1));
    float h0 = __uint_as_float(h << 16);
    float h1 = __uint_as_float(h & 0xFFFF0000u);
    float r0 = f0 - h0, r1 = f1 - h1;
    uint32_t l;
    asm("v_cvt_pk_bf16_f32 %0, %1, %2" : "=v"(l) : "v"(r0), "v"(r1));
    hp = h; lp = l;
}

__device__ __forceinline__ unsigned long long shflxor64(unsigned long long v, int off) {
    unsigned lo = (unsigned)v, hi = (unsigned)(v >> 32);
    lo = (unsigned)__shfl_xor((int)lo, off);
    hi = (unsigned)__shfl_xor((int)hi, off);
    return ((unsigned long long)hi << 32) | lo;
}

// ---- kernel 1: cnorm (exact pairwise) + fragment-ordered bf16 hi/lo ----
__global__ __launch_bounds__(256) void vq_prep_kernel(
    const float* __restrict__ cb, unsigned char* __restrict__ ws) {
#pragma clang fp contract(off)
    const int k = blockIdx.x * 256 + threadIdx.x;   // grid = 4 blocks
    const float4* row4 = (const float4*)(cb + k * CDIM);
    float v[CDIM];
#pragma unroll
    for (int i = 0; i < 16; ++i) {
        float4 t = row4[i];
        v[i * 4 + 0] = t.x; v[i * 4 + 1] = t.y;
        v[i * 4 + 2] = t.z; v[i * 4 + 3] = t.w;
    }
    float r[8];
#pragma unroll
    for (int j = 0; j < 8; ++j) r[j] = v[j] * v[j];
#pragma unroll
    for (int i = 1; i < 8; ++i) {
#pragma unroll
        for (int j = 0; j < 8; ++j) {
            float s = v[i * 8 + j] * v[i * 8 + j];
            r[j] = r[j] + s;
        }
    }
    const float cn =
        ((r[0] + r[1]) + (r[2] + r[3])) + ((r[4] + r[5]) + (r[6] + r[7]));
    ((float*)(ws + WS_CNORM))[k] = cn;
    ((float*)(ws + WS_CNB))[k]   = cn + BIAS;

    // fragment-order split: code k = kt*16 + rr; slot s (dims s*8..s*8+7):
    //   ks = s>>2, lane = (s&3)*16 + rr
    const int kt = k >> 4, rr = k & 15;
    unsigned char* base = ws + WS_CBF + kt * 4096;
#pragma unroll
    for (int s = 0; s < 8; ++s) {
        U4S8 H, L;
        uint32_t hp, lp;
        cvt_pair(v[s * 8 + 0], v[s * 8 + 1], hp, lp); H.u.x = hp; L.u.x = lp;
        cvt_pair(v[s * 8 + 2], v[s * 8 + 3], hp, lp); H.u.y = hp; L.u.y = lp;
        cvt_pair(v[s * 8 + 4], v[s * 8 + 5], hp, lp); H.u.z = hp; L.u.z = lp;
        cvt_pair(v[s * 8 + 6], v[s * 8 + 7], hp, lp); H.u.w = hp; L.u.w = lp;
        const int ks   = s >> 2;
        const int lane = (s & 3) * 16 + rr;
        unsigned char* hi_dst = base + ks * 2048 + lane * 16;
        *(uint4*)(hi_dst)        = H.u;
        *(uint4*)(hi_dst + 1024) = L.u;
    }
}

// ---- LDS layout (bytes) ----
#define LDS_TILE 0         // 32*65*4 = 8320 (epilogue; overlays nothing live)
#define LDS_WRED 8320      // 32 pos * 5 slots * 8 B (float2, pad 5) = 1280
#define LDS_SFIN 9600      // 32 int
#define LDS_AMBC 9728
#define LDS_AMBL 9744      // 32 int
#define LDS_ZSC  9872      // pad to 16B: use 9888
#define LDS_ZSC16 9888     // 4 waves * 64 f32 = 1024
#define SMEM_SZ  10912

// ---- kernel 2: main ----
__global__ __launch_bounds__(256, 2) void vq_main_kernel(
    const float* __restrict__ in, const float* __restrict__ cb,
    const unsigned char* __restrict__ ws, float* __restrict__ out) {
#pragma clang fp contract(off)
    const int tid  = threadIdx.x;
    const int lane = tid & 63;
    const int wv   = tid >> 6;          // 0..3 = k-quarter
    const int l15  = lane & 15;
    const int lg   = lane >> 4;         // 0..3
    const int n0g  = blockIdx.x * NPB;
    const int b    = n0g >> 12;
    const int hw0  = n0g & 4095;

    __shared__ __align__(16) unsigned char smem[SMEM_SZ];
    float2* wred   = (float2*)(smem + LDS_WRED);
    int*   sfin    = (int*)(smem + LDS_SFIN);
    int*   ambcnt  = (int*)(smem + LDS_AMBC);
    int*   amblist = (int*)(smem + LDS_AMBL);
    float* zsc     = (float*)(smem + LDS_ZSC16);
    const unsigned char* cbf = ws + WS_CBF;
    const float* cnorm = (const float*)(ws + WS_CNORM);
    const float* cnb_g = (const float*)(ws + WS_CNB);

    if (tid == 0) *ambcnt = 0;

    // ---- z frags from global: block owns 32 positions (2 n-frags/wave) ----
    // lane l, n-frag na: position na*16 + l15, dim-slot ks*4+lg
    short8 zfh[2][2], zfl[2][2];   // [na][ks]
#pragma unroll
    for (int na = 0; na < 2; ++na) {
        const int pos = na * 16 + l15;
#pragma unroll
        for (int ks = 0; ks < 2; ++ks) {
            const int sl = ks * 4 + lg;
            const float* zp = in + (((size_t)(b * CDIM + sl * 8)) << 12) + hw0 + pos;
            float f[8];
#pragma unroll
            for (int j = 0; j < 8; ++j) f[j] = zp[(size_t)j << 12];
            U4S8 H, L;
            uint32_t hp, lp;
            cvt_pair(f[0], f[1], hp, lp); H.u.x = hp; L.u.x = lp;
            cvt_pair(f[2], f[3], hp, lp); H.u.y = hp; L.u.y = lp;
            cvt_pair(f[4], f[5], hp, lp); H.u.z = hp; L.u.z = lp;
            cvt_pair(f[6], f[7], hp, lp); H.u.w = hp; L.u.w = lp;
            zfh[na][ks] = H.s; zfl[na][ks] = L.s;
        }
    }

    const float finf = __uint_as_float(0x7F800000u);
    float m1[2] = {finf, finf}, m2[2] = {finf, finf};

    // ---- main loop: 16 ktiles of this wave's quarter, reg double-buffered,
    //      zero barriers, straight from L2 ----
    const unsigned char* qb = cbf + (size_t)wv * 65536 + (size_t)lane * 16;
    U4S8 ch0, cl0, ch1, cl1;
    ch0.u = *(const uint4*)(qb);
    cl0.u = *(const uint4*)(qb + 1024);
    ch1.u = *(const uint4*)(qb + 2048);
    cl1.u = *(const uint4*)(qb + 3072);

    for (int kt = 0; kt < 16; ++kt) {
        U4S8 nh0, nl0, nh1, nl1;
        if (kt < 15) {
            const unsigned char* fb = qb + (kt + 1) * 4096;
            nh0.u = *(const uint4*)(fb);
            nl0.u = *(const uint4*)(fb + 1024);
            nh1.u = *(const uint4*)(fb + 2048);
            nl1.u = *(const uint4*)(fb + 3072);
        }

        const int kb = (wv * 16 + kt) * 16 + lg * 4;   // global code base
        const f32x4 cn = *(const f32x4*)(cnb_g + kb);

        f32x4 a0 = {0.f, 0.f, 0.f, 0.f}, a1 = {0.f, 0.f, 0.f, 0.f};
        a0 = __builtin_amdgcn_mfma_f32_16x16x32_bf16(cl0.s, zfh[0][0], a0, 0, 0, 0);
        a1 = __builtin_amdgcn_mfma_f32_16x16x32_bf16(cl0.s, zfh[1][0], a1, 0, 0, 0);
        a0 = __builtin_amdgcn_mfma_f32_16x16x32_bf16(ch0.s, zfl[0][0], a0, 0, 0, 0);
        a1 = __builtin_amdgcn_mfma_f32_16x16x32_bf16(ch0.s, zfl[1][0], a1, 0, 0, 0);
        a0 = __builtin_amdgcn_mfma_f32_16x16x32_bf16(ch0.s, zfh[0][0], a0, 0, 0, 0);
        a1 = __builtin_amdgcn_mfma_f32_16x16x32_bf16(ch0.s, zfh[1][0], a1, 0, 0, 0);
        a0 = __builtin_amdgcn_mfma_f32_16x16x32_bf16(cl1.s, zfh[0][1], a0, 0, 0, 0);
        a1 = __builtin_amdgcn_mfma_f32_16x16x32_bf16(cl1.s, zfh[1][1], a1, 0, 0, 0);
        a0 = __builtin_amdgcn_mfma_f32_16x16x32_bf16(ch1.s, zfl[0][1], a0, 0, 0, 0);
        a1 = __builtin_amdgcn_mfma_f32_16x16x32_bf16(ch1.s, zfl[1][1], a1, 0, 0, 0);
        a0 = __builtin_amdgcn_mfma_f32_16x16x32_bf16(ch1.s, zfh[0][1], a0, 0, 0, 0);
        a1 = __builtin_amdgcn_mfma_f32_16x16x32_bf16(ch1.s, zfh[1][1], a1, 0, 0, 0);

#pragma unroll
        for (int r = 0; r < 4; ++r) {
            float s0 = fmaf(-2.0f, a0[r], cn[r]);
            float k0 = __uint_as_float(
                (__float_as_uint(s0) & 0xFFFFFC00u) | (uint32_t)(kb + r));
            m2[0] = fminf(m2[0], fmaxf(k0, m1[0]));
            m1[0] = fminf(m1[0], k0);
            float s1 = fmaf(-2.0f, a1[r], cn[r]);
            float k1 = __uint_as_float(
                (__float_as_uint(s1) & 0xFFFFFC00u) | (uint32_t)(kb + r));
            m2[1] = fminf(m2[1], fmaxf(k1, m1[1]));
            m1[1] = fminf(m1[1], k1);
        }

        ch0 = nh0; cl0 = nl0; ch1 = nh1; cl1 = nl1;
    }

    // ---- merge the 4 lane-groups (this wave's quarter is complete) ----
#pragma unroll
    for (int na = 0; na < 2; ++na) {
#pragma unroll
        for (int off = 16; off <= 32; off <<= 1) {
            float o1 = __shfl_xor(m1[na], off);
            float o2 = __shfl_xor(m2[na], off);
            m2[na] = fminf(fminf(m2[na], o2), fmaxf(m1[na], o1));
            m1[na] = fminf(m1[na], o1);
        }
    }

    // ---- park this wave's (m1,m2) per position; cross-wave merge ----
    if (lg == 0) {
#pragma unroll
        for (int na = 0; na < 2; ++na) {
            float2 w; w.x = m1[na]; w.y = m2[na];
            wred[(na * 16 + l15) * 5 + wv] = w;
        }
    }
    __syncthreads();

    if (tid < NPB) {
        float c1 = finf, c2 = finf;
#pragma unroll
        for (int w = 0; w < 4; ++w) {
            float2 v = wred[tid * 5 + w];
            c2 = fminf(fminf(c2, v.y), fmaxf(c1, v.x));
            c1 = fminf(c1, v.x);
        }
        const uint32_t u1 = __float_as_uint(c1);
        const int idx = (int)(u1 & 1023u);
        sfin[tid] = idx;
        out[n0g + tid] = (float)idx;
        const float v1 = __uint_as_float(u1 & 0xFFFFFC00u);
        const float v2 = __uint_as_float(__float_as_uint(c2) & 0xFFFFFC00u);
        if (v2 - v1 < DELTA) {
            int p = atomicAdd(ambcnt, 1);
            amblist[p] = tid;
        }
    }
    __syncthreads();

    // ---- exact rescreen, wave-parallel (r7/r9-validated numerics) ----
    const int namb = *ambcnt;
    for (int i = wv; i < namb; i += 4) {
        const int n = amblist[i];
        float zc = in[(((size_t)(b * CDIM + lane)) << 12) + hw0 + n];
        float sq = zc * zc;
        float accp = sq;
#pragma unroll
        for (int i2 = 1; i2 < 8; ++i2)
            accp = accp + __shfl(sq, i2 * 8 + (lane & 7));
        float t1 = accp + __shfl_xor(accp, 1);
        float t2 = t1 + __shfl_xor(t1, 2);
        float t3 = t2 + __shfl_xor(t2, 4);
        const float zn = __shfl(t3, 0);
        zsc[wv * 64 + lane] = zc;
        const float* zrow = &zsc[wv * 64];
        unsigned long long bestk = ~0ull;
        for (int j = 0; j < 16; ++j) {
            const int k = j * 64 + lane;
            const float4* e = (const float4*)(cb + (size_t)k * CDIM);
            float a0 = 0.f, a1 = 0.f, a2 = 0.f, a3 = 0.f;
#pragma unroll
            for (int i2 = 0; i2 < 4; ++i2) {
                float4 zz = *(const float4*)(zrow + i2 * 16);
                float4 z1 = *(const float4*)(zrow + i2 * 16 + 4);
                float4 z2 = *(const float4*)(zrow + i2 * 16 + 8);
                float4 z3 = *(const float4*)(zrow + i2 * 16 + 12);
                float4 v0 = e[i2 * 4 + 0];
                float4 v1 = e[i2 * 4 + 1];
                float4 v2 = e[i2 * 4 + 2];
                float4 v3 = e[i2 * 4 + 3];
                a0 = fmaf(zz.x, v0.x, a0); a0 = fmaf(zz.y, v0.y, a0);
                a0 = fmaf(zz.z, v0.z, a0); a0 = fmaf(zz.w, v0.w, a0);
                a1 = fmaf(z1.x, v1.x, a1); a1 = fmaf(z1.y, v1.y, a1);
                a1 = fmaf(z1.z, v1.z, a1); a1 = fmaf(z1.w, v1.w, a1);
                a2 = fmaf(z2.x, v2.x, a2); a2 = fmaf(z2.y, v2.y, a2);
                a2 = fmaf(z2.z, v2.z, a2); a2 = fmaf(z2.w, v2.w, a2);
                a3 = fmaf(z3.x, v3.x, a3); a3 = fmaf(z3.y, v3.y, a3);
                a3 = fmaf(z3.z, v3.z, a3); a3 = fmaf(z3.w, v3.w, a3);
            }
            float dot = (a0 + a1) + (a2 + a3);
            float t = zn + cnorm[k];   // fl(znorm + cnorm)
            float u = 2.0f * dot;      // fl(2*dot)
            float d = t - u;           // fl(t - u)
            unsigned long long key =
                ((unsigned long long)__float_as_uint(d) << 10) | (unsigned)k;
            bestk = key < bestk ? key : bestk;
        }
#pragma unroll
        for (int off = 32; off >= 1; off >>= 1) {
            unsigned long long o = shflxor64(bestk, off);
            bestk = o < bestk ? o : bestk;
        }
        if (lane == 0) {
            const int idx = (int)(bestk & 1023u);
            sfin[n] = idx;
            out[n0g + n] = (float)idx;
        }
    }
    __syncthreads();

    // ---- zqs epilogue: gather -> LDS tile [32][65] -> coalesced BCHW ----
    float (*tile)[65] = (float (*)[65])(smem + LDS_TILE);
    {
        const int p = tid >> 3, e8 = tid & 7;     // p: 0..31, e8: eighth of row
        const int idx = sfin[p];
        const float4* row = (const float4*)(cb + (size_t)idx * CDIM) + e8 * 2;
#pragma unroll
        for (int i = 0; i < 2; ++i) {
            float4 v = row[i];
            const int cch = e8 * 8 + i * 4;
            tile[p][cch + 0] = v.x; tile[p][cch + 1] = v.y;
            tile[p][cch + 2] = v.z; tile[p][cch + 3] = v.w;
        }
    }
    __syncthreads();
    {
        // thread t: pos = t&31, c = (t>>5) + i*8  (per instr: 2 x 128B runs)
        const int pos = tid & 31, cg = tid >> 5;
        float* zq = out + NPOS + (((size_t)b * CDIM) << 12) + hw0;
#pragma unroll
        for (int i = 0; i < 8; ++i) {
            const int cch = i * 8 + cg;
            zq[((size_t)cch << 12) + pos] = tile[pos][cch];
        }
    }
}

extern "C" void kernel_launch(void* const* d_in, const int* in_sizes, int n_in,
                              void* d_out, int out_size, void* d_ws, size_t ws_size,
                              hipStream_t stream) {
    const float* in = (const float*)d_in[0];   // 16*64*64*64
    const float* cb = (const float*)d_in[1];   // 1024*64
    float* out = (float*)d_out;                // 65536 + 4194304
    unsigned char* ws = (unsigned char*)d_ws;  // ~264 KB used

    vq_prep_kernel<<<NUM_K / 256, 256, 0, stream>>>(cb, ws);
    vq_main_kernel<<<NPOS / NPB, 256, 0, stream>>>(in, cb, ws, out);
}

// Round 12
// 81.643 us; speedup vs baseline: 2.0492x; 1.8782x over previous
//
#include <hip/hip_runtime.h>
#include <stdint.h>

// VQ: inputs (16,64,64,64) f32 BCHW, codebook (1024,64) f32.
// out[0:65536] = argmin indices as float; out[65536:] = gathered rows, BCHW.
//
// r12 = r11 with the ws-overlap crash fixed: flag counter + flagged list now
// live in the zqs region of `out` (aux = (int*)(out+NPOS)), which K4 fully
// overwrites afterwards. ws usage stays at the r6/r10-proven 270336 bytes.
//  K1 prep:    cnorm (exact pairwise) + fragment-ordered bf16 hi/lo split
//              + zero aux[0].
//  K2 filter:  r10-validated MFMA filter loop; integer keys
//              trunc(s*2^22)<<10|k (quantum 2.4e-7); gap < ILIM=128
//              (~3.05e-5 > required ~1.9e-5) -> append to aux list.
//  K3 rescreen: grid-strided waves over flagged list; r7-validated exact
//              body (bit-exact numpy znorm, t/u/d fp32 order, u64 keys).
//  K4 zqs:     r7-validated gather -> LDS transpose -> coalesced BCHW
//              (overwrites the aux region).
#define NUM_K 1024
#define CDIM  64
#define NPOS  65536
#define NPB   32
#define BIAS  0.25f          // s = cnorm+BIAS-2dot in [0.08,0.42] > 0
#define QS    4194304.0f     // 2^22: s*QS < 2^21 -> key = q<<10|k fits u32
#define ILIM  128            // quantized gap < 128*2^-22 ~ 3.05e-5 -> rescreen

typedef __attribute__((ext_vector_type(8))) short short8;
typedef __attribute__((ext_vector_type(4))) float f32x4;

union U4S8 { uint4 u; short8 s; };

// ---- d_ws layout (bytes) — total 270336, proven size ----
#define WS_CNORM 0           // 1024 f32 exact
#define WS_CNB   4096        // 1024 f32 (cnorm + BIAS)
#define WS_CBF   8192        // 64 ktiles * 4096 B = [8192, 270336)
                             //  +0:ks0 hi +1024:ks0 lo +2048:ks1 hi +3072:ks1 lo

__device__ __forceinline__ void cvt_pair(float f0, float f1,
                                         uint32_t& hp, uint32_t& lp) {
    uint32_t h;
    asm("v_cvt_pk_bf16_f32 %0, %1, %2" : "=v"(h) : "v"(f0), "v"(f1));
    float h0 = __uint_as_float(h << 16);
    float h1 = __uint_as_float(h & 0xFFFF0000u);
    float r0 = f0 - h0, r1 = f1 - h1;
    uint32_t l;
    asm("v_cvt_pk_bf16_f32 %0, %1, %2" : "=v"(l) : "v"(r0), "v"(r1));
    hp = h; lp = l;
}

__device__ __forceinline__ unsigned long long shflxor64(unsigned long long v, int off) {
    unsigned lo = (unsigned)v, hi = (unsigned)(v >> 32);
    lo = (unsigned)__shfl_xor((int)lo, off);
    hi = (unsigned)__shfl_xor((int)hi, off);
    return ((unsigned long long)hi << 32) | lo;
}

// ---- K1: cnorm (exact pairwise) + fragment-ordered bf16 hi/lo + aux[0]=0 ----
__global__ __launch_bounds__(256) void vq_prep_kernel(
    const float* __restrict__ cb, unsigned char* __restrict__ ws,
    float* __restrict__ out) {
#pragma clang fp contract(off)
    const int k = blockIdx.x * 256 + threadIdx.x;   // grid = 4 blocks
    if (k == 0) ((int*)(out + NPOS))[0] = 0;        // flag counter in out aux
    const float4* row4 = (const float4*)(cb + k * CDIM);
    float v[CDIM];
#pragma unroll
    for (int i = 0; i < 16; ++i) {
        float4 t = row4[i];
        v[i * 4 + 0] = t.x; v[i * 4 + 1] = t.y;
        v[i * 4 + 2] = t.z; v[i * 4 + 3] = t.w;
    }
    float r[8];
#pragma unroll
    for (int j = 0; j < 8; ++j) r[j] = v[j] * v[j];
#pragma unroll
    for (int i = 1; i < 8; ++i) {
#pragma unroll
        for (int j = 0; j < 8; ++j) {
            float s = v[i * 8 + j] * v[i * 8 + j];
            r[j] = r[j] + s;
        }
    }
    const float cn =
        ((r[0] + r[1]) + (r[2] + r[3])) + ((r[4] + r[5]) + (r[6] + r[7]));
    ((float*)(ws + WS_CNORM))[k] = cn;
    ((float*)(ws + WS_CNB))[k]   = cn + BIAS;

    const int kt = k >> 4, rr = k & 15;
    unsigned char* base = ws + WS_CBF + kt * 4096;
#pragma unroll
    for (int s = 0; s < 8; ++s) {
        U4S8 H, L;
        uint32_t hp, lp;
        cvt_pair(v[s * 8 + 0], v[s * 8 + 1], hp, lp); H.u.x = hp; L.u.x = lp;
        cvt_pair(v[s * 8 + 2], v[s * 8 + 3], hp, lp); H.u.y = hp; L.u.y = lp;
        cvt_pair(v[s * 8 + 4], v[s * 8 + 5], hp, lp); H.u.z = hp; L.u.z = lp;
        cvt_pair(v[s * 8 + 6], v[s * 8 + 7], hp, lp); H.u.w = hp; L.u.w = lp;
        const int ks   = s >> 2;
        const int lane = (s & 3) * 16 + rr;
        unsigned char* hi_dst = base + ks * 2048 + lane * 16;
        *(uint4*)(hi_dst)        = H.u;
        *(uint4*)(hi_dst + 1024) = L.u;
    }
}

// ---- K2: filter (r10 loop, integer keys; flags -> out aux list) ----
__global__ __launch_bounds__(256, 4) void vq_filter_kernel(
    const float* __restrict__ in, const unsigned char* __restrict__ ws,
    float* __restrict__ out) {
#pragma clang fp contract(off)
    const int tid  = threadIdx.x;
    const int lane = tid & 63;
    const int wv   = tid >> 6;          // 0..3 = k-quarter
    const int l15  = lane & 15;
    const int lg   = lane >> 4;         // 0..3
    const int n0g  = blockIdx.x * NPB;
    const int b    = n0g >> 12;
    const int hw0  = n0g & 4095;

    __shared__ uint2 wred[NPB][5];      // [pos][quarter] pad 5

    const unsigned char* cbf = ws + WS_CBF;
    const float* cnb_g = (const float*)(ws + WS_CNB);
    int* aux = (int*)(out + NPOS);      // [0]=count, [1..]=flagged positions

    // z frags from global: block owns 32 positions (2 n-frags/wave)
    short8 zfh[2][2], zfl[2][2];   // [na][ks]
#pragma unroll
    for (int na = 0; na < 2; ++na) {
        const int pos = na * 16 + l15;
#pragma unroll
        for (int ks = 0; ks < 2; ++ks) {
            const int sl = ks * 4 + lg;
            const float* zp = in + (((size_t)(b * CDIM + sl * 8)) << 12) + hw0 + pos;
            float f[8];
#pragma unroll
            for (int j = 0; j < 8; ++j) f[j] = zp[(size_t)j << 12];
            U4S8 H, L;
            uint32_t hp, lp;
            cvt_pair(f[0], f[1], hp, lp); H.u.x = hp; L.u.x = lp;
            cvt_pair(f[2], f[3], hp, lp); H.u.y = hp; L.u.y = lp;
            cvt_pair(f[4], f[5], hp, lp); H.u.z = hp; L.u.z = lp;
            cvt_pair(f[6], f[7], hp, lp); H.u.w = hp; L.u.w = lp;
            zfh[na][ks] = H.s; zfl[na][ks] = L.s;
        }
    }

    uint32_t m1[2] = {0xFFFFFFFFu, 0xFFFFFFFFu};
    uint32_t m2[2] = {0xFFFFFFFFu, 0xFFFFFFFFu};

    // main loop: 16 ktiles of this wave's quarter, reg double-buffered
    const unsigned char* qb = cbf + (size_t)wv * 65536 + (size_t)lane * 16;
    U4S8 ch0, cl0, ch1, cl1;
    ch0.u = *(const uint4*)(qb);
    cl0.u = *(const uint4*)(qb + 1024);
    ch1.u = *(const uint4*)(qb + 2048);
    cl1.u = *(const uint4*)(qb + 3072);

    for (int kt = 0; kt < 16; ++kt) {
        U4S8 nh0, nl0, nh1, nl1;
        if (kt < 15) {
            const unsigned char* fb = qb + (kt + 1) * 4096;
            nh0.u = *(const uint4*)(fb);
            nl0.u = *(const uint4*)(fb + 1024);
            nh1.u = *(const uint4*)(fb + 2048);
            nl1.u = *(const uint4*)(fb + 3072);
        }

        const int kb = (wv * 16 + kt) * 16 + lg * 4;   // global code base
        const f32x4 cn = *(const f32x4*)(cnb_g + kb);

        f32x4 a0 = {0.f, 0.f, 0.f, 0.f}, a1 = {0.f, 0.f, 0.f, 0.f};
        a0 = __builtin_amdgcn_mfma_f32_16x16x32_bf16(cl0.s, zfh[0][0], a0, 0, 0, 0);
        a1 = __builtin_amdgcn_mfma_f32_16x16x32_bf16(cl0.s, zfh[1][0], a1, 0, 0, 0);
        a0 = __builtin_amdgcn_mfma_f32_16x16x32_bf16(ch0.s, zfl[0][0], a0, 0, 0, 0);
        a1 = __builtin_amdgcn_mfma_f32_16x16x32_bf16(ch0.s, zfl[1][0], a1, 0, 0, 0);
        a0 = __builtin_amdgcn_mfma_f32_16x16x32_bf16(ch0.s, zfh[0][0], a0, 0, 0, 0);
        a1 = __builtin_amdgcn_mfma_f32_16x16x32_bf16(ch0.s, zfh[1][0], a1, 0, 0, 0);
        a0 = __builtin_amdgcn_mfma_f32_16x16x32_bf16(cl1.s, zfh[0][1], a0, 0, 0, 0);
        a1 = __builtin_amdgcn_mfma_f32_16x16x32_bf16(cl1.s, zfh[1][1], a1, 0, 0, 0);
        a0 = __builtin_amdgcn_mfma_f32_16x16x32_bf16(ch1.s, zfl[0][1], a0, 0, 0, 0);
        a1 = __builtin_amdgcn_mfma_f32_16x16x32_bf16(ch1.s, zfl[1][1], a1, 0, 0, 0);
        a0 = __builtin_amdgcn_mfma_f32_16x16x32_bf16(ch1.s, zfh[0][1], a0, 0, 0, 0);
        a1 = __builtin_amdgcn_mfma_f32_16x16x32_bf16(ch1.s, zfh[1][1], a1, 0, 0, 0);

#pragma unroll
        for (int r = 0; r < 4; ++r) {
            float s0 = fmaf(-2.0f, a0[r], cn[r]);
            uint32_t k0 = ((uint32_t)(s0 * QS) << 10) | (uint32_t)(kb + r);
            m2[0] = min(m2[0], max(k0, m1[0]));
            m1[0] = min(m1[0], k0);
            float s1 = fmaf(-2.0f, a1[r], cn[r]);
            uint32_t k1 = ((uint32_t)(s1 * QS) << 10) | (uint32_t)(kb + r);
            m2[1] = min(m2[1], max(k1, m1[1]));
            m1[1] = min(m1[1], k1);
        }

        ch0 = nh0; cl0 = nl0; ch1 = nh1; cl1 = nl1;
    }

    // merge the 4 lane-groups (quarter complete per wave)
#pragma unroll
    for (int na = 0; na < 2; ++na) {
#pragma unroll
        for (int off = 16; off <= 32; off <<= 1) {
            uint32_t o1 = (uint32_t)__shfl_xor((int)m1[na], off);
            uint32_t o2 = (uint32_t)__shfl_xor((int)m2[na], off);
            m2[na] = min(min(m2[na], o2), max(m1[na], o1));
            m1[na] = min(m1[na], o1);
        }
    }

    if (lg == 0) {
#pragma unroll
        for (int na = 0; na < 2; ++na) {
            uint2 w; w.x = m1[na]; w.y = m2[na];
            wred[na * 16 + l15][wv] = w;
        }
    }
    __syncthreads();

    // cross-wave merge, zis write, global flagging
    if (tid < NPB) {
        uint32_t c1 = 0xFFFFFFFFu, c2 = 0xFFFFFFFFu;
#pragma unroll
        for (int w = 0; w < 4; ++w) {
            uint2 v = wred[tid][w];
            c2 = min(c2, min(v.y, max(c1, v.x)));
            c1 = min(c1, v.x);
        }
        const int idx = (int)(c1 & 1023u);
        out[n0g + tid] = (float)idx;
        if ((c2 >> 10) - (c1 >> 10) < ILIM) {
            int p = atomicAdd(aux, 1);
            aux[1 + p] = n0g + tid;
        }
    }
}

// ---- K3: exact rescreen of flagged positions (r7-validated numerics) ----
__global__ __launch_bounds__(256, 4) void vq_rescreen_kernel(
    const float* __restrict__ in, const float* __restrict__ cb,
    const unsigned char* __restrict__ ws, float* __restrict__ out) {
#pragma clang fp contract(off)
    const int tid  = threadIdx.x;
    const int lane = tid & 63;
    const int wv   = tid >> 6;
    const int gw   = blockIdx.x * 4 + wv;     // 1024 waves total

    __shared__ __align__(16) float zsc[4][64];
    const int* aux = (const int*)(out + NPOS);
    const int namb = aux[0];
    const float* cnorm = (const float*)(ws + WS_CNORM);

    for (int i = gw; i < namb; i += 1024) {
        const int n  = aux[1 + i];
        const int b  = n >> 12;
        const int hw = n & 4095;
        float zc = in[(((size_t)(b * CDIM + lane)) << 12) + hw];
        // bit-exact numpy pairwise znorm via shfl
        float sq = zc * zc;
        float accp = sq;
#pragma unroll
        for (int i2 = 1; i2 < 8; ++i2)
            accp = accp + __shfl(sq, i2 * 8 + (lane & 7));
        float t1 = accp + __shfl_xor(accp, 1);
        float t2 = t1 + __shfl_xor(t1, 2);
        float t3 = t2 + __shfl_xor(t2, 4);
        const float zn = __shfl(t3, 0);
        zsc[wv][lane] = zc;
        const float* zrow = &zsc[wv][0];
        unsigned long long bestk = ~0ull;
        for (int j = 0; j < 16; ++j) {
            const int k = j * 64 + lane;
            const float4* e = (const float4*)(cb + (size_t)k * CDIM);
            float a0 = 0.f, a1 = 0.f, a2 = 0.f, a3 = 0.f;
#pragma unroll
            for (int i2 = 0; i2 < 4; ++i2) {
                float4 zz = *(const float4*)(zrow + i2 * 16);
                float4 z1 = *(const float4*)(zrow + i2 * 16 + 4);
                float4 z2 = *(const float4*)(zrow + i2 * 16 + 8);
                float4 z3 = *(const float4*)(zrow + i2 * 16 + 12);
                float4 v0 = e[i2 * 4 + 0];
                float4 v1 = e[i2 * 4 + 1];
                float4 v2 = e[i2 * 4 + 2];
                float4 v3 = e[i2 * 4 + 3];
                a0 = fmaf(zz.x, v0.x, a0); a0 = fmaf(zz.y, v0.y, a0);
                a0 = fmaf(zz.z, v0.z, a0); a0 = fmaf(zz.w, v0.w, a0);
                a1 = fmaf(z1.x, v1.x, a1); a1 = fmaf(z1.y, v1.y, a1);
                a1 = fmaf(z1.z, v1.z, a1); a1 = fmaf(z1.w, v1.w, a1);
                a2 = fmaf(z2.x, v2.x, a2); a2 = fmaf(z2.y, v2.y, a2);
                a2 = fmaf(z2.z, v2.z, a2); a2 = fmaf(z2.w, v2.w, a2);
                a3 = fmaf(z3.x, v3.x, a3); a3 = fmaf(z3.y, v3.y, a3);
                a3 = fmaf(z3.z, v3.z, a3); a3 = fmaf(z3.w, v3.w, a3);
            }
            float dot = (a0 + a1) + (a2 + a3);
            float t = zn + cnorm[k];   // fl(znorm + cnorm)
            float u = 2.0f * dot;      // fl(2*dot)
            float d = t - u;           // fl(t - u)
            unsigned long long key =
                ((unsigned long long)__float_as_uint(d) << 10) | (unsigned)k;
            bestk = key < bestk ? key : bestk;
        }
#pragma unroll
        for (int off = 32; off >= 1; off >>= 1) {
            unsigned long long o = shflxor64(bestk, off);
            bestk = o < bestk ? o : bestk;
        }
        if (lane == 0) out[n] = (float)(int)(bestk & 1023u);
    }
}

// ---- K4: zqs epilogue: gather -> LDS transpose -> coalesced BCHW ----
__global__ __launch_bounds__(256, 4) void vq_zqs_kernel(
    const float* __restrict__ cb, float* __restrict__ out) {
    const int tid  = threadIdx.x;
    const int lane = tid & 63;
    const int wv   = tid >> 6;
    const int n0g  = blockIdx.x * 64;
    const int b    = n0g >> 12;
    const int hw0  = n0g & 4095;

    __shared__ float tile[64][65];
    __shared__ int sfin[64];
    if (tid < 64) sfin[tid] = (int)out[n0g + tid];   // float<=1023 exact
    __syncthreads();
    {
        const int p = tid >> 2, q4 = tid & 3;
        const int idx = sfin[p];
        const float4* row = (const float4*)(cb + (size_t)idx * CDIM) + q4 * 4;
#pragma unroll
        for (int i = 0; i < 4; ++i) {
            float4 v = row[i];
            const int cch = q4 * 16 + i * 4;
            tile[p][cch + 0] = v.x; tile[p][cch + 1] = v.y;
            tile[p][cch + 2] = v.z; tile[p][cch + 3] = v.w;
        }
    }
    __syncthreads();
    {
        float* zq = out + NPOS + (((size_t)b * CDIM) << 12) + hw0;
#pragma unroll
        for (int i = 0; i < 16; ++i) {
            const int cch = i * 4 + wv;
            zq[((size_t)cch << 12) + lane] = tile[lane][cch];
        }
    }
}

extern "C" void kernel_launch(void* const* d_in, const int* in_sizes, int n_in,
                              void* d_out, int out_size, void* d_ws, size_t ws_size,
                              hipStream_t stream) {
    const float* in = (const float*)d_in[0];   // 16*64*64*64
    const float* cb = (const float*)d_in[1];   // 1024*64
    float* out = (float*)d_out;                // 65536 + 4194304
    unsigned char* ws = (unsigned char*)d_ws;  // 270336 bytes (proven size)

    vq_prep_kernel<<<NUM_K / 256, 256, 0, stream>>>(cb, ws, out);
    vq_filter_kernel<<<NPOS / NPB, 256, 0, stream>>>(in, ws, out);
    vq_rescreen_kernel<<<256, 256, 0, stream>>>(in, cb, ws, out);
    vq_zqs_kernel<<<NPOS / 64, 256, 0, stream>>>(cb, out);
}

// Round 13
// 81.439 us; speedup vs baseline: 2.0543x; 1.0025x over previous
//
#include <hip/hip_runtime.h>
#include <stdint.h>

// VQ: inputs (16,64,64,64) f32 BCHW, codebook (1024,64) f32.
// out[0:65536] = argmin indices as float; out[65536:] = gathered rows, BCHW.
//
// r13 pipeline (r12-validated numerics throughout):
//  K1 prep (16x64): cnorm + cnq=(cnorm+BIAS)*QS + fragment-ordered bf16
//     hi/lo codebook in ws + zero flag counter.
//  K2 filter: r12-validated MFMA filter; fused int keys
//     trunc(fmaf(-2*QS,acc,cnq))<<10|k (quantum 2.4e-7); paired exact
//     (min1,min2) update; writes zis + zqs-for-all (LDS transpose, skipping
//     the carved channel) + flag list.
//  Flag list lives in the CARVED zqs channel (b=15,c=63) = last 4096 floats
//     of out: K2 never writes those cells, K3 consumes the list and fixes
//     flagged rows, K4 patches the carved channel from final zis.
//  K3 rescreen: grid-strided waves; r7-validated exact body (bit-exact
//     numpy znorm, t/u/d fp32 order, u64 keys); also rewrites zqs row.
//  K4 patch: 4096 cells of the carved channel.
#define NUM_K 1024
#define CDIM  64
#define NPOS  65536
#define NPB   32
#define BIAS  0.25f          // s = cnorm+BIAS-2dot in [0.08,0.42] > 0
#define QS    4194304.0f     // 2^22: s*QS < 2^21 -> key = q<<10|k fits u32
#define ILIM  128            // quantized gap < 128*2^-22 ~ 3.05e-5 -> rescreen
#define AUXOFF 4255744       // out index of carved channel (b=15,c=63): last 4096 floats
#define CARVE_N0 61440       // positions n>=61440 are b==15

typedef __attribute__((ext_vector_type(8))) short short8;
typedef __attribute__((ext_vector_type(4))) float f32x4;

union U4S8 { uint4 u; short8 s; };

// ---- d_ws layout (bytes) — total 270336, proven size ----
#define WS_CNORM 0           // 1024 f32 exact
#define WS_CNQ   4096        // 1024 f32: (cnorm + BIAS) * QS
#define WS_CBF   8192        // 64 ktiles * 4096 B = [8192, 270336)
                             //  +0:ks0 hi +1024:ks0 lo +2048:ks1 hi +3072:ks1 lo

__device__ __forceinline__ void cvt_pair(float f0, float f1,
                                         uint32_t& hp, uint32_t& lp) {
    uint32_t h;
    asm("v_cvt_pk_bf16_f32 %0, %1, %2" : "=v"(h) : "v"(f0), "v"(f1));
    float h0 = __uint_as_float(h << 16);
    float h1 = __uint_as_float(h & 0xFFFF0000u);
    float r0 = f0 - h0, r1 = f1 - h1;
    uint32_t l;
    asm("v_cvt_pk_bf16_f32 %0, %1, %2" : "=v"(l) : "v"(r0), "v"(r1));
    hp = h; lp = l;
}

__device__ __forceinline__ unsigned long long shflxor64(unsigned long long v, int off) {
    unsigned lo = (unsigned)v, hi = (unsigned)(v >> 32);
    lo = (unsigned)__shfl_xor((int)lo, off);
    hi = (unsigned)__shfl_xor((int)hi, off);
    return ((unsigned long long)hi << 32) | lo;
}

// ---- K1: cnorm + cnq + fragment-ordered bf16 hi/lo + counter=0 ----
__global__ __launch_bounds__(64) void vq_prep_kernel(
    const float* __restrict__ cb, unsigned char* __restrict__ ws,
    float* __restrict__ out) {
#pragma clang fp contract(off)
    const int k = blockIdx.x * 64 + threadIdx.x;    // grid = 16 blocks
    if (k == 0) ((int*)(out + AUXOFF))[0] = 0;      // flag counter
    const float4* row4 = (const float4*)(cb + k * CDIM);
    float v[CDIM];
#pragma unroll
    for (int i = 0; i < 16; ++i) {
        float4 t = row4[i];
        v[i * 4 + 0] = t.x; v[i * 4 + 1] = t.y;
        v[i * 4 + 2] = t.z; v[i * 4 + 3] = t.w;
    }
    float r[8];
#pragma unroll
    for (int j = 0; j < 8; ++j) r[j] = v[j] * v[j];
#pragma unroll
    for (int i = 1; i < 8; ++i) {
#pragma unroll
        for (int j = 0; j < 8; ++j) {
            float s = v[i * 8 + j] * v[i * 8 + j];
            r[j] = r[j] + s;
        }
    }
    const float cn =
        ((r[0] + r[1]) + (r[2] + r[3])) + ((r[4] + r[5]) + (r[6] + r[7]));
    ((float*)(ws + WS_CNORM))[k] = cn;
    ((float*)(ws + WS_CNQ))[k]   = (cn + BIAS) * QS;

    const int kt = k >> 4, rr = k & 15;
    unsigned char* base = ws + WS_CBF + kt * 4096;
#pragma unroll
    for (int s = 0; s < 8; ++s) {
        U4S8 H, L;
        uint32_t hp, lp;
        cvt_pair(v[s * 8 + 0], v[s * 8 + 1], hp, lp); H.u.x = hp; L.u.x = lp;
        cvt_pair(v[s * 8 + 2], v[s * 8 + 3], hp, lp); H.u.y = hp; L.u.y = lp;
        cvt_pair(v[s * 8 + 4], v[s * 8 + 5], hp, lp); H.u.z = hp; L.u.z = lp;
        cvt_pair(v[s * 8 + 6], v[s * 8 + 7], hp, lp); H.u.w = hp; L.u.w = lp;
        const int ks   = s >> 2;
        const int lane = (s & 3) * 16 + rr;
        unsigned char* hi_dst = base + ks * 2048 + lane * 16;
        *(uint4*)(hi_dst)        = H.u;
        *(uint4*)(hi_dst + 1024) = L.u;
    }
}

// ---- K2: filter + zis + zqs-for-all + flags ----
__global__ __launch_bounds__(256, 4) void vq_filter_kernel(
    const float* __restrict__ in, const float* __restrict__ cb,
    const unsigned char* __restrict__ ws, float* __restrict__ out) {
#pragma clang fp contract(off)
    const int tid  = threadIdx.x;
    const int lane = tid & 63;
    const int wv   = tid >> 6;          // 0..3 = k-quarter
    const int l15  = lane & 15;
    const int lg   = lane >> 4;         // 0..3
    const int n0g  = blockIdx.x * NPB;
    const int b    = n0g >> 12;
    const int hw0  = n0g & 4095;

    __shared__ uint2 wred[NPB][5];      // [pos][quarter] pad 5
    __shared__ int   sfin[NPB];
    __shared__ float tile[NPB][65];

    const unsigned char* cbf = ws + WS_CBF;
    const float* cnq_g = (const float*)(ws + WS_CNQ);
    int* aux = (int*)(out + AUXOFF);    // [0]=count, [1..4095]=flagged

    // z frags from global: block owns 32 positions (2 n-frags/wave)
    short8 zfh[2][2], zfl[2][2];   // [na][ks]
#pragma unroll
    for (int na = 0; na < 2; ++na) {
        const int pos = na * 16 + l15;
#pragma unroll
        for (int ks = 0; ks < 2; ++ks) {
            const int sl = ks * 4 + lg;
            const float* zp = in + (((size_t)(b * CDIM + sl * 8)) << 12) + hw0 + pos;
            float f[8];
#pragma unroll
            for (int j = 0; j < 8; ++j) f[j] = zp[(size_t)j << 12];
            U4S8 H, L;
            uint32_t hp, lp;
            cvt_pair(f[0], f[1], hp, lp); H.u.x = hp; L.u.x = lp;
            cvt_pair(f[2], f[3], hp, lp); H.u.y = hp; L.u.y = lp;
            cvt_pair(f[4], f[5], hp, lp); H.u.z = hp; L.u.z = lp;
            cvt_pair(f[6], f[7], hp, lp); H.u.w = hp; L.u.w = lp;
            zfh[na][ks] = H.s; zfl[na][ks] = L.s;
        }
    }

    uint32_t m1[2] = {0xFFFFFFFFu, 0xFFFFFFFFu};
    uint32_t m2[2] = {0xFFFFFFFFu, 0xFFFFFFFFu};

    // main loop: 16 ktiles of this wave's quarter, reg double-buffered
    const unsigned char* qb = cbf + (size_t)wv * 65536 + (size_t)lane * 16;
    U4S8 ch0, cl0, ch1, cl1;
    ch0.u = *(const uint4*)(qb);
    cl0.u = *(const uint4*)(qb + 1024);
    ch1.u = *(const uint4*)(qb + 2048);
    cl1.u = *(const uint4*)(qb + 3072);

    for (int kt = 0; kt < 16; ++kt) {
        U4S8 nh0, nl0, nh1, nl1;
        if (kt < 15) {
            const unsigned char* fb = qb + (kt + 1) * 4096;
            nh0.u = *(const uint4*)(fb);
            nl0.u = *(const uint4*)(fb + 1024);
            nh1.u = *(const uint4*)(fb + 2048);
            nl1.u = *(const uint4*)(fb + 3072);
        }

        const int kb = (wv * 16 + kt) * 16 + lg * 4;   // global code base
        const f32x4 cq = *(const f32x4*)(cnq_g + kb);

        f32x4 a0 = {0.f, 0.f, 0.f, 0.f}, a1 = {0.f, 0.f, 0.f, 0.f};
        a0 = __builtin_amdgcn_mfma_f32_16x16x32_bf16(cl0.s, zfh[0][0], a0, 0, 0, 0);
        a1 = __builtin_amdgcn_mfma_f32_16x16x32_bf16(cl0.s, zfh[1][0], a1, 0, 0, 0);
        a0 = __builtin_amdgcn_mfma_f32_16x16x32_bf16(ch0.s, zfl[0][0], a0, 0, 0, 0);
        a1 = __builtin_amdgcn_mfma_f32_16x16x32_bf16(ch0.s, zfl[1][0], a1, 0, 0, 0);
        a0 = __builtin_amdgcn_mfma_f32_16x16x32_bf16(ch0.s, zfh[0][0], a0, 0, 0, 0);
        a1 = __builtin_amdgcn_mfma_f32_16x16x32_bf16(ch0.s, zfh[1][0], a1, 0, 0, 0);
        a0 = __builtin_amdgcn_mfma_f32_16x16x32_bf16(cl1.s, zfh[0][1], a0, 0, 0, 0);
        a1 = __builtin_amdgcn_mfma_f32_16x16x32_bf16(cl1.s, zfh[1][1], a1, 0, 0, 0);
        a0 = __builtin_amdgcn_mfma_f32_16x16x32_bf16(ch1.s, zfl[0][1], a0, 0, 0, 0);
        a1 = __builtin_amdgcn_mfma_f32_16x16x32_bf16(ch1.s, zfl[1][1], a1, 0, 0, 0);
        a0 = __builtin_amdgcn_mfma_f32_16x16x32_bf16(ch1.s, zfh[0][1], a0, 0, 0, 0);
        a1 = __builtin_amdgcn_mfma_f32_16x16x32_bf16(ch1.s, zfh[1][1], a1, 0, 0, 0);

        // fused int keys + exact paired (min1,min2) update
#pragma unroll
        for (int r = 0; r < 4; r += 2) {
            uint32_t ka = ((uint32_t)fmaf(-2.0f * QS, a0[r],     cq[r])     << 10) | (uint32_t)(kb + r);
            uint32_t kc = ((uint32_t)fmaf(-2.0f * QS, a0[r + 1], cq[r + 1]) << 10) | (uint32_t)(kb + r + 1);
            uint32_t lo = min(ka, kc), hi = max(ka, kc);
            m2[0] = min(min(m2[0], hi), max(lo, m1[0]));
            m1[0] = min(m1[0], lo);
            uint32_t kd = ((uint32_t)fmaf(-2.0f * QS, a1[r],     cq[r])     << 10) | (uint32_t)(kb + r);
            uint32_t ke = ((uint32_t)fmaf(-2.0f * QS, a1[r + 1], cq[r + 1]) << 10) | (uint32_t)(kb + r + 1);
            uint32_t lo1 = min(kd, ke), hi1 = max(kd, ke);
            m2[1] = min(min(m2[1], hi1), max(lo1, m1[1]));
            m1[1] = min(m1[1], lo1);
        }

        ch0 = nh0; cl0 = nl0; ch1 = nh1; cl1 = nl1;
    }

    // merge the 4 lane-groups (quarter complete per wave)
#pragma unroll
    for (int na = 0; na < 2; ++na) {
#pragma unroll
        for (int off = 16; off <= 32; off <<= 1) {
            uint32_t o1 = (uint32_t)__shfl_xor((int)m1[na], off);
            uint32_t o2 = (uint32_t)__shfl_xor((int)m2[na], off);
            m2[na] = min(min(m2[na], o2), max(m1[na], o1));
            m1[na] = min(m1[na], o1);
        }
    }

    if (lg == 0) {
#pragma unroll
        for (int na = 0; na < 2; ++na) {
            uint2 w; w.x = m1[na]; w.y = m2[na];
            wred[na * 16 + l15][wv] = w;
        }
    }
    __syncthreads();

    // cross-wave merge, zis write, flagging
    if (tid < NPB) {
        uint32_t c1 = 0xFFFFFFFFu, c2 = 0xFFFFFFFFu;
#pragma unroll
        for (int w = 0; w < 4; ++w) {
            uint2 v = wred[tid][w];
            c2 = min(c2, min(v.y, max(c1, v.x)));
            c1 = min(c1, v.x);
        }
        const int idx = (int)(c1 & 1023u);
        sfin[tid] = idx;
        out[n0g + tid] = (float)idx;
        if ((c2 >> 10) - (c1 >> 10) < ILIM) {
            int p = atomicAdd(aux, 1);
            if (p < 4095) aux[1 + p] = n0g + tid;
        }
    }
    __syncthreads();

    // zqs epilogue: gather -> LDS transpose -> coalesced BCHW (skip carve)
    {
        const int p = tid >> 3, e8 = tid & 7;
        const int idx = sfin[p];
        const float4* row = (const float4*)(cb + (size_t)idx * CDIM) + e8 * 2;
        float4 v0 = row[0], v1 = row[1];
        const int c0 = e8 * 8;
        tile[p][c0 + 0] = v0.x; tile[p][c0 + 1] = v0.y;
        tile[p][c0 + 2] = v0.z; tile[p][c0 + 3] = v0.w;
        tile[p][c0 + 4] = v1.x; tile[p][c0 + 5] = v1.y;
        tile[p][c0 + 6] = v1.z; tile[p][c0 + 7] = v1.w;
    }
    __syncthreads();
    {
        const int pos = tid & 31, cg = tid >> 5;   // cg 0..7
        float* zq = out + NPOS + (((size_t)b * CDIM) << 12) + hw0;
#pragma unroll
        for (int i = 0; i < 8; ++i) {
            const int cch = i * 8 + cg;
            if (!(b == 15 && cch == 63))           // carved channel
                zq[((size_t)cch << 12) + pos] = tile[pos][cch];
        }
    }
}

// ---- K3: exact rescreen of flagged positions + zqs row fix ----
__global__ __launch_bounds__(256, 4) void vq_rescreen_kernel(
    const float* __restrict__ in, const float* __restrict__ cb,
    const unsigned char* __restrict__ ws, float* __restrict__ out) {
#pragma clang fp contract(off)
    const int tid  = threadIdx.x;
    const int lane = tid & 63;
    const int wv   = tid >> 6;
    const int gw   = blockIdx.x * 4 + wv;     // 1024 waves total

    __shared__ __align__(16) float zsc[4][64];
    const int* aux = (const int*)(out + AUXOFF);
    const int namb = min(aux[0], 4095);
    const float* cnorm = (const float*)(ws + WS_CNORM);

    for (int i = gw; i < namb; i += 1024) {
        const int n  = aux[1 + i];
        const int b  = n >> 12;
        const int hw = n & 4095;
        float zc = in[(((size_t)(b * CDIM + lane)) << 12) + hw];
        // bit-exact numpy pairwise znorm via shfl
        float sq = zc * zc;
        float accp = sq;
#pragma unroll
        for (int i2 = 1; i2 < 8; ++i2)
            accp = accp + __shfl(sq, i2 * 8 + (lane & 7));
        float t1 = accp + __shfl_xor(accp, 1);
        float t2 = t1 + __shfl_xor(t1, 2);
        float t3 = t2 + __shfl_xor(t2, 4);
        const float zn = __shfl(t3, 0);
        zsc[wv][lane] = zc;
        const float* zrow = &zsc[wv][0];
        unsigned long long bestk = ~0ull;
        for (int j = 0; j < 16; ++j) {
            const int k = j * 64 + lane;
            const float4* e = (const float4*)(cb + (size_t)k * CDIM);
            float a0 = 0.f, a1 = 0.f, a2 = 0.f, a3 = 0.f;
#pragma unroll
            for (int i2 = 0; i2 < 4; ++i2) {
                float4 zz = *(const float4*)(zrow + i2 * 16);
                float4 z1 = *(const float4*)(zrow + i2 * 16 + 4);
                float4 z2 = *(const float4*)(zrow + i2 * 16 + 8);
                float4 z3 = *(const float4*)(zrow + i2 * 16 + 12);
                float4 v0 = e[i2 * 4 + 0];
                float4 v1 = e[i2 * 4 + 1];
                float4 v2 = e[i2 * 4 + 2];
                float4 v3 = e[i2 * 4 + 3];
                a0 = fmaf(zz.x, v0.x, a0); a0 = fmaf(zz.y, v0.y, a0);
                a0 = fmaf(zz.z, v0.z, a0); a0 = fmaf(zz.w, v0.w, a0);
                a1 = fmaf(z1.x, v1.x, a1); a1 = fmaf(z1.y, v1.y, a1);
                a1 = fmaf(z1.z, v1.z, a1); a1 = fmaf(z1.w, v1.w, a1);
                a2 = fmaf(z2.x, v2.x, a2); a2 = fmaf(z2.y, v2.y, a2);
                a2 = fmaf(z2.z, v2.z, a2); a2 = fmaf(z2.w, v2.w, a2);
                a3 = fmaf(z3.x, v3.x, a3); a3 = fmaf(z3.y, v3.y, a3);
                a3 = fmaf(z3.z, v3.z, a3); a3 = fmaf(z3.w, v3.w, a3);
            }
            float dot = (a0 + a1) + (a2 + a3);
            float t = zn + cnorm[k];   // fl(znorm + cnorm)
            float u = 2.0f * dot;      // fl(2*dot)
            float d = t - u;           // fl(t - u)
            unsigned long long key =
                ((unsigned long long)__float_as_uint(d) << 10) | (unsigned)k;
            bestk = key < bestk ? key : bestk;
        }
#pragma unroll
        for (int off = 32; off >= 1; off >>= 1) {
            unsigned long long o = shflxor64(bestk, off);
            bestk = o < bestk ? o : bestk;
        }
        const int idx = (int)(bestk & 1023u);
        if (lane == 0) out[n] = (float)idx;
        // fix zqs row (skip carved cell; K4 patches it from final zis)
        float val = cb[idx * CDIM + lane];
        if (!(n >= CARVE_N0 && lane == 63))
            out[NPOS + (((size_t)(b * CDIM + lane)) << 12) + hw] = val;
    }
}

// ---- K4: patch the carved channel (b=15, c=63) from final zis ----
__global__ __launch_bounds__(256) void vq_patch_kernel(
    const float* __restrict__ cb, float* __restrict__ out) {
    const int hw = blockIdx.x * 256 + threadIdx.x;   // grid = 16 blocks
    const int idx = (int)out[CARVE_N0 + hw];
    out[AUXOFF + hw] = cb[idx * CDIM + 63];
}

extern "C" void kernel_launch(void* const* d_in, const int* in_sizes, int n_in,
                              void* d_out, int out_size, void* d_ws, size_t ws_size,
                              hipStream_t stream) {
    const float* in = (const float*)d_in[0];   // 16*64*64*64
    const float* cb = (const float*)d_in[1];   // 1024*64
    float* out = (float*)d_out;                // 65536 + 4194304
    unsigned char* ws = (unsigned char*)d_ws;  // 270336 bytes (proven size)

    vq_prep_kernel<<<16, 64, 0, stream>>>(cb, ws, out);
    vq_filter_kernel<<<NPOS / NPB, 256, 0, stream>>>(in, cb, ws, out);
    vq_rescreen_kernel<<<256, 256, 0, stream>>>(in, cb, ws, out);
    vq_patch_kernel<<<16, 256, 0, stream>>>(cb, out);
}

// Round 14
// 68.774 us; speedup vs baseline: 2.4327x; 1.1842x over previous
//
#include <hip/hip_runtime.h>
#include <stdint.h>

// VQ: inputs (16,64,64,64) f32 BCHW, codebook (1024,64) f32.
// out[0:65536] = argmin indices as float; out[65536:] = gathered rows, BCHW.
//
// r14 pipeline (r12/r13-validated numerics):
//  K1 prep: cnorm + cnq=(cnorm+BIAS)*QS + fragment-ordered bf16 hi/lo split
//     in ws + TRANSPOSED f32 codebook cbT[c][k] + flag counter, both in the
//     CARVED b=15 zqs region of out (1 MB; rebuilt by K4 at the end).
//  K2 filter: MFMA filter, depth-2 register prefetch, 4 independent 3-MFMA
//     chains; int keys trunc(fmaf(-2QS,acc,cnq))<<10|k; writes zis for all +
//     zqs for b<15 + flag list. (ILIM=128 ~ 3.05e-5 >= required ~1.76e-5.)
//  K3 rescreen: COALESCED exact rescreen via cbT (lane l owns codes
//     j*256+4l..+3; float4 column reads); bit-exact numpy znorm; t/u/d fp32
//     order; u64 first-occurrence keys; fixes zqs rows for b<15.
//  K4 patch: rebuilds the whole b=15 zqs image from final zis.
#define NUM_K 1024
#define CDIM  64
#define NPOS  65536
#define NPB   32
#define BIAS  0.25f          // s = cnorm+BIAS-2dot in [0.08,0.42] > 0
#define QS    4194304.0f     // 2^22: key = trunc(s*QS)<<10 | k fits u32
#define ILIM  128            // quantized gap < 128*2^-22 ~ 3.05e-5 -> rescreen
#define CARVE_N0 61440       // positions n>=61440 are b==15
#define CBT0  3997696        // out idx: b=15 zqs region start; cbT[c][k] 64x1024
#define AUXC  4063232        // out idx: flag counter (int), list follows

typedef __attribute__((ext_vector_type(8))) short short8;
typedef __attribute__((ext_vector_type(4))) float f32x4;

union U4S8 { uint4 u; short8 s; };

// ---- d_ws layout (bytes) — total 270336, proven size ----
#define WS_CNORM 0           // 1024 f32 exact
#define WS_CNQ   4096        // 1024 f32: (cnorm + BIAS) * QS
#define WS_CBF   8192        // 64 ktiles * 4096 B = [8192, 270336)

__device__ __forceinline__ void cvt_pair(float f0, float f1,
                                         uint32_t& hp, uint32_t& lp) {
    uint32_t h;
    asm("v_cvt_pk_bf16_f32 %0, %1, %2" : "=v"(h) : "v"(f0), "v"(f1));
    float h0 = __uint_as_float(h << 16);
    float h1 = __uint_as_float(h & 0xFFFF0000u);
    float r0 = f0 - h0, r1 = f1 - h1;
    uint32_t l;
    asm("v_cvt_pk_bf16_f32 %0, %1, %2" : "=v"(l) : "v"(r0), "v"(r1));
    hp = h; lp = l;
}

__device__ __forceinline__ unsigned long long shflxor64(unsigned long long v, int off) {
    unsigned lo = (unsigned)v, hi = (unsigned)(v >> 32);
    lo = (unsigned)__shfl_xor((int)lo, off);
    hi = (unsigned)__shfl_xor((int)hi, off);
    return ((unsigned long long)hi << 32) | lo;
}

// ---- K1: cnorm + cnq + bf16 frag split + cbT + counter=0 ----
__global__ __launch_bounds__(64) void vq_prep_kernel(
    const float* __restrict__ cb, unsigned char* __restrict__ ws,
    float* __restrict__ out) {
#pragma clang fp contract(off)
    const int k = blockIdx.x * 64 + threadIdx.x;    // grid = 16 blocks
    if (k == 0) ((int*)(out + AUXC))[0] = 0;
    const float4* row4 = (const float4*)(cb + k * CDIM);
    float v[CDIM];
#pragma unroll
    for (int i = 0; i < 16; ++i) {
        float4 t = row4[i];
        v[i * 4 + 0] = t.x; v[i * 4 + 1] = t.y;
        v[i * 4 + 2] = t.z; v[i * 4 + 3] = t.w;
    }
    float r[8];
#pragma unroll
    for (int j = 0; j < 8; ++j) r[j] = v[j] * v[j];
#pragma unroll
    for (int i = 1; i < 8; ++i) {
#pragma unroll
        for (int j = 0; j < 8; ++j) {
            float s = v[i * 8 + j] * v[i * 8 + j];
            r[j] = r[j] + s;
        }
    }
    const float cn =
        ((r[0] + r[1]) + (r[2] + r[3])) + ((r[4] + r[5]) + (r[6] + r[7]));
    ((float*)(ws + WS_CNORM))[k] = cn;
    ((float*)(ws + WS_CNQ))[k]   = (cn + BIAS) * QS;

    // transposed f32 codebook in carved region (coalesced per c across block)
#pragma unroll 8
    for (int c = 0; c < CDIM; ++c)
        out[CBT0 + c * 1024 + k] = v[c];

    const int kt = k >> 4, rr = k & 15;
    unsigned char* base = ws + WS_CBF + kt * 4096;
#pragma unroll
    for (int s = 0; s < 8; ++s) {
        U4S8 H, L;
        uint32_t hp, lp;
        cvt_pair(v[s * 8 + 0], v[s * 8 + 1], hp, lp); H.u.x = hp; L.u.x = lp;
        cvt_pair(v[s * 8 + 2], v[s * 8 + 3], hp, lp); H.u.y = hp; L.u.y = lp;
        cvt_pair(v[s * 8 + 4], v[s * 8 + 5], hp, lp); H.u.z = hp; L.u.z = lp;
        cvt_pair(v[s * 8 + 6], v[s * 8 + 7], hp, lp); H.u.w = hp; L.u.w = lp;
        const int ks   = s >> 2;
        const int lane = (s & 3) * 16 + rr;
        unsigned char* hi_dst = base + ks * 2048 + lane * 16;
        *(uint4*)(hi_dst)        = H.u;
        *(uint4*)(hi_dst + 1024) = L.u;
    }
}

#define MFMA16(A, B, C) __builtin_amdgcn_mfma_f32_16x16x32_bf16(A, B, C, 0, 0, 0)

#define LOADT(H0, L0, H1, L1, addr) {                   \
    const unsigned char* fb_ = (addr);                  \
    H0.u = *(const uint4*)(fb_);                        \
    L0.u = *(const uint4*)(fb_ + 1024);                 \
    H1.u = *(const uint4*)(fb_ + 2048);                 \
    L1.u = *(const uint4*)(fb_ + 3072);                 \
}

#define COMPT(H0, L0, H1, L1, KT) {                                           \
    const int kb_ = (wv * 16 + (KT)) * 16 + lg * 4;                           \
    const f32x4 cq_ = *(const f32x4*)(cnq_g + kb_);                           \
    f32x4 p00 = {0.f,0.f,0.f,0.f}, p01 = {0.f,0.f,0.f,0.f};                   \
    f32x4 p10 = {0.f,0.f,0.f,0.f}, p11 = {0.f,0.f,0.f,0.f};                   \
    p00 = MFMA16(L0.s, zfh[0][0], p00); p10 = MFMA16(L0.s, zfh[1][0], p10);   \
    p01 = MFMA16(L1.s, zfh[0][1], p01); p11 = MFMA16(L1.s, zfh[1][1], p11);   \
    p00 = MFMA16(H0.s, zfl[0][0], p00); p10 = MFMA16(H0.s, zfl[1][0], p10);   \
    p01 = MFMA16(H1.s, zfl[0][1], p01); p11 = MFMA16(H1.s, zfl[1][1], p11);   \
    p00 = MFMA16(H0.s, zfh[0][0], p00); p10 = MFMA16(H0.s, zfh[1][0], p10);   \
    p01 = MFMA16(H1.s, zfh[0][1], p01); p11 = MFMA16(H1.s, zfh[1][1], p11);   \
    f32x4 a0_, a1_;                                                           \
    a0_[0] = p00[0] + p01[0]; a0_[1] = p00[1] + p01[1];                       \
    a0_[2] = p00[2] + p01[2]; a0_[3] = p00[3] + p01[3];                       \
    a1_[0] = p10[0] + p11[0]; a1_[1] = p10[1] + p11[1];                       \
    a1_[2] = p10[2] + p11[2]; a1_[3] = p10[3] + p11[3];                       \
    _Pragma("unroll")                                                         \
    for (int r = 0; r < 4; r += 2) {                                          \
        uint32_t ka = ((uint32_t)fmaf(-2.0f * QS, a0_[r],     cq_[r])     << 10) | (uint32_t)(kb_ + r);     \
        uint32_t kc = ((uint32_t)fmaf(-2.0f * QS, a0_[r + 1], cq_[r + 1]) << 10) | (uint32_t)(kb_ + r + 1); \
        uint32_t lo_ = min(ka, kc), hi_ = max(ka, kc);                        \
        m2[0] = min(min(m2[0], hi_), max(lo_, m1[0]));                        \
        m1[0] = min(m1[0], lo_);                                              \
        uint32_t kd = ((uint32_t)fmaf(-2.0f * QS, a1_[r],     cq_[r])     << 10) | (uint32_t)(kb_ + r);     \
        uint32_t ke = ((uint32_t)fmaf(-2.0f * QS, a1_[r + 1], cq_[r + 1]) << 10) | (uint32_t)(kb_ + r + 1); \
        uint32_t lo1_ = min(kd, ke), hi1_ = max(kd, ke);                      \
        m2[1] = min(min(m2[1], hi1_), max(lo1_, m1[1]));                      \
        m1[1] = min(m1[1], lo1_);                                             \
    }                                                                         \
}

// ---- K2: filter + zis + zqs (b<15) + flags ----
__global__ __launch_bounds__(256, 4) void vq_filter_kernel(
    const float* __restrict__ in, const float* __restrict__ cb,
    const unsigned char* __restrict__ ws, float* __restrict__ out) {
#pragma clang fp contract(off)
    const int tid  = threadIdx.x;
    const int lane = tid & 63;
    const int wv   = tid >> 6;          // 0..3 = k-quarter
    const int l15  = lane & 15;
    const int lg   = lane >> 4;         // 0..3
    const int n0g  = blockIdx.x * NPB;
    const int b    = n0g >> 12;
    const int hw0  = n0g & 4095;

    __shared__ uint2 wred[NPB][5];
    __shared__ int   sfin[NPB];
    __shared__ float tile[NPB][65];

    const unsigned char* cbf = ws + WS_CBF;
    const float* cnq_g = (const float*)(ws + WS_CNQ);
    int* auxp = (int*)(out + AUXC);

    // z frags from global: block owns 32 positions (2 n-frags/wave)
    short8 zfh[2][2], zfl[2][2];   // [na][ks]
#pragma unroll
    for (int na = 0; na < 2; ++na) {
        const int pos = na * 16 + l15;
#pragma unroll
        for (int ks = 0; ks < 2; ++ks) {
            const int sl = ks * 4 + lg;
            const float* zp = in + (((size_t)(b * CDIM + sl * 8)) << 12) + hw0 + pos;
            float f[8];
#pragma unroll
            for (int j = 0; j < 8; ++j) f[j] = zp[(size_t)j << 12];
            U4S8 H, L;
            uint32_t hp, lp;
            cvt_pair(f[0], f[1], hp, lp); H.u.x = hp; L.u.x = lp;
            cvt_pair(f[2], f[3], hp, lp); H.u.y = hp; L.u.y = lp;
            cvt_pair(f[4], f[5], hp, lp); H.u.z = hp; L.u.z = lp;
            cvt_pair(f[6], f[7], hp, lp); H.u.w = hp; L.u.w = lp;
            zfh[na][ks] = H.s; zfl[na][ks] = L.s;
        }
    }

    uint32_t m1[2] = {0xFFFFFFFFu, 0xFFFFFFFFu};
    uint32_t m2[2] = {0xFFFFFFFFu, 0xFFFFFFFFu};

    // main loop: 16 ktiles, depth-2 register prefetch (named A/B buffers)
    const unsigned char* qb = cbf + (size_t)wv * 65536 + (size_t)lane * 16;
    U4S8 Ah0, Al0, Ah1, Al1, Bh0, Bl0, Bh1, Bl1;
    LOADT(Ah0, Al0, Ah1, Al1, qb);
    LOADT(Bh0, Bl0, Bh1, Bl1, qb + 4096);

#pragma unroll
    for (int kt = 0; kt < 16; kt += 2) {
        U4S8 Nh0, Nl0, Nh1, Nl1, Mh0, Ml0, Mh1, Ml1;
        if (kt + 2 < 16) LOADT(Nh0, Nl0, Nh1, Nl1, qb + (kt + 2) * 4096);
        COMPT(Ah0, Al0, Ah1, Al1, kt);
        if (kt + 3 < 16) LOADT(Mh0, Ml0, Mh1, Ml1, qb + (kt + 3) * 4096);
        COMPT(Bh0, Bl0, Bh1, Bl1, kt + 1);
        Ah0 = Nh0; Al0 = Nl0; Ah1 = Nh1; Al1 = Nl1;
        Bh0 = Mh0; Bl0 = Ml0; Bh1 = Mh1; Bl1 = Ml1;
    }

    // merge the 4 lane-groups (quarter complete per wave)
#pragma unroll
    for (int na = 0; na < 2; ++na) {
#pragma unroll
        for (int off = 16; off <= 32; off <<= 1) {
            uint32_t o1 = (uint32_t)__shfl_xor((int)m1[na], off);
            uint32_t o2 = (uint32_t)__shfl_xor((int)m2[na], off);
            m2[na] = min(min(m2[na], o2), max(m1[na], o1));
            m1[na] = min(m1[na], o1);
        }
    }

    if (lg == 0) {
#pragma unroll
        for (int na = 0; na < 2; ++na) {
            uint2 w; w.x = m1[na]; w.y = m2[na];
            wred[na * 16 + l15][wv] = w;
        }
    }
    __syncthreads();

    // cross-wave merge, zis write, flagging
    if (tid < NPB) {
        uint32_t c1 = 0xFFFFFFFFu, c2 = 0xFFFFFFFFu;
#pragma unroll
        for (int w = 0; w < 4; ++w) {
            uint2 v = wred[tid][w];
            c2 = min(c2, min(v.y, max(c1, v.x)));
            c1 = min(c1, v.x);
        }
        const int idx = (int)(c1 & 1023u);
        sfin[tid] = idx;
        out[n0g + tid] = (float)idx;
        if ((c2 >> 10) - (c1 >> 10) < ILIM) {
            int p = atomicAdd(auxp, 1);
            auxp[1 + p] = n0g + tid;
        }
    }

    if (b == 15) return;   // carved image: K4 rebuilds it from final zis
    __syncthreads();

    // zqs epilogue: gather -> LDS transpose -> coalesced BCHW
    {
        const int p = tid >> 3, e8 = tid & 7;
        const int idx = sfin[p];
        const float4* row = (const float4*)(cb + (size_t)idx * CDIM) + e8 * 2;
        float4 v0 = row[0], v1 = row[1];
        const int c0 = e8 * 8;
        tile[p][c0 + 0] = v0.x; tile[p][c0 + 1] = v0.y;
        tile[p][c0 + 2] = v0.z; tile[p][c0 + 3] = v0.w;
        tile[p][c0 + 4] = v1.x; tile[p][c0 + 5] = v1.y;
        tile[p][c0 + 6] = v1.z; tile[p][c0 + 7] = v1.w;
    }
    __syncthreads();
    {
        const int pos = tid & 31, cg = tid >> 5;
        float* zq = out + NPOS + (((size_t)b * CDIM) << 12) + hw0;
#pragma unroll
        for (int i = 0; i < 8; ++i) {
            const int cch = i * 8 + cg;
            zq[((size_t)cch << 12) + pos] = tile[pos][cch];
        }
    }
}

// ---- K3: coalesced exact rescreen via cbT ----
__global__ __launch_bounds__(256, 4) void vq_rescreen_kernel(
    const float* __restrict__ in, const float* __restrict__ cb,
    const unsigned char* __restrict__ ws, float* __restrict__ out) {
#pragma clang fp contract(off)
    const int tid  = threadIdx.x;
    const int lane = tid & 63;
    const int wv   = tid >> 6;
    const int gw   = blockIdx.x * 4 + wv;     // 1024 waves total

    __shared__ __align__(16) float zsc[4][64];
    const int* auxp = (const int*)(out + AUXC);
    const int namb = auxp[0];
    const float* cnorm = (const float*)(ws + WS_CNORM);
    const float* cbT = out + CBT0;            // [c][k] 64 x 1024

    for (int i = gw; i < namb; i += 1024) {
        const int n  = auxp[1 + i];
        const int b  = n >> 12;
        const int hw = n & 4095;
        float zc = in[(((size_t)(b * CDIM + lane)) << 12) + hw];
        // bit-exact numpy pairwise znorm via shfl (r7-validated)
        float sq = zc * zc;
        float accp = sq;
#pragma unroll
        for (int i2 = 1; i2 < 8; ++i2)
            accp = accp + __shfl(sq, i2 * 8 + (lane & 7));
        float t1 = accp + __shfl_xor(accp, 1);
        float t2 = t1 + __shfl_xor(t1, 2);
        float t3 = t2 + __shfl_xor(t2, 4);
        const float zn = __shfl(t3, 0);
        zsc[wv][lane] = zc;

        // lane owns codes j*256 + 4*lane + r (j<4, r<4); coalesced float4 cols
        f32x4 accA = {0.f,0.f,0.f,0.f}, accB = {0.f,0.f,0.f,0.f};
        f32x4 accC = {0.f,0.f,0.f,0.f}, accD = {0.f,0.f,0.f,0.f};
#pragma unroll 4
        for (int c = 0; c < CDIM; ++c) {
            const float zv = zsc[wv][c];
            const float* col = cbT + c * 1024 + 4 * lane;
            f32x4 qA = *(const f32x4*)(col);
            f32x4 qB = *(const f32x4*)(col + 256);
            f32x4 qC = *(const f32x4*)(col + 512);
            f32x4 qD = *(const f32x4*)(col + 768);
#pragma unroll
            for (int r = 0; r < 4; ++r) {
                accA[r] = fmaf(zv, qA[r], accA[r]);
                accB[r] = fmaf(zv, qB[r], accB[r]);
                accC[r] = fmaf(zv, qC[r], accC[r]);
                accD[r] = fmaf(zv, qD[r], accD[r]);
            }
        }

        unsigned long long bestk = ~0ull;
#pragma unroll
        for (int j = 0; j < 4; ++j) {
            const f32x4 cnv = *(const f32x4*)(cnorm + j * 256 + 4 * lane);
            const f32x4 acc = (j == 0) ? accA : (j == 1) ? accB : (j == 2) ? accC : accD;
#pragma unroll
            for (int r = 0; r < 4; ++r) {
                const int k = j * 256 + 4 * lane + r;
                float t = zn + cnv[r];     // fl(znorm + cnorm)
                float u = 2.0f * acc[r];   // fl(2*dot)
                float d = t - u;           // fl(t - u)
                unsigned long long key =
                    ((unsigned long long)__float_as_uint(d) << 10) | (unsigned)k;
                bestk = key < bestk ? key : bestk;
            }
        }
#pragma unroll
        for (int off = 32; off >= 1; off >>= 1) {
            unsigned long long o = shflxor64(bestk, off);
            bestk = o < bestk ? o : bestk;
        }
        const int idx = (int)(bestk & 1023u);
        if (lane == 0) out[n] = (float)idx;
        if (n < CARVE_N0) {   // b=15 rows are rebuilt wholesale by K4
            float val = cb[idx * CDIM + lane];
            out[NPOS + (((size_t)(b * CDIM + lane)) << 12) + hw] = val;
        }
    }
}

// ---- K4: rebuild the b=15 zqs image from final zis ----
__global__ __launch_bounds__(256) void vq_patch_kernel(
    const float* __restrict__ cb, float* __restrict__ out) {
    const int tid  = threadIdx.x;
    const int lane = tid & 63;
    const int wv   = tid >> 6;
    const int p0   = CARVE_N0 + blockIdx.x * 64;   // grid = 64 blocks
    const int hw0  = p0 & 4095;

    __shared__ float tile[64][65];
    __shared__ int sfin[64];
    if (tid < 64) sfin[tid] = (int)out[p0 + tid];
    __syncthreads();
    {
        const int p = tid >> 2, q4 = tid & 3;
        const int idx = sfin[p];
        const float4* row = (const float4*)(cb + (size_t)idx * CDIM) + q4 * 4;
#pragma unroll
        for (int i = 0; i < 4; ++i) {
            float4 v = row[i];
            const int cch = q4 * 16 + i * 4;
            tile[p][cch + 0] = v.x; tile[p][cch + 1] = v.y;
            tile[p][cch + 2] = v.z; tile[p][cch + 3] = v.w;
        }
    }
    __syncthreads();
    {
        float* zq = out + NPOS + (((size_t)15 * CDIM) << 12) + hw0;
#pragma unroll
        for (int i = 0; i < 16; ++i) {
            const int cch = i * 4 + wv;
            zq[((size_t)cch << 12) + lane] = tile[lane][cch];
        }
    }
}

extern "C" void kernel_launch(void* const* d_in, const int* in_sizes, int n_in,
                              void* d_out, int out_size, void* d_ws, size_t ws_size,
                              hipStream_t stream) {
    const float* in = (const float*)d_in[0];   // 16*64*64*64
    const float* cb = (const float*)d_in[1];   // 1024*64
    float* out = (float*)d_out;                // 65536 + 4194304
    unsigned char* ws = (unsigned char*)d_ws;  // 270336 bytes (proven size)

    vq_prep_kernel<<<16, 64, 0, stream>>>(cb, ws, out);
    vq_filter_kernel<<<NPOS / NPB, 256, 0, stream>>>(in, cb, ws, out);
    vq_rescreen_kernel<<<256, 256, 0, stream>>>(in, cb, ws, out);
    vq_patch_kernel<<<64, 256, 0, stream>>>(cb, out);
}